// Round 11
// baseline (374.936 us; speedup 1.0000x reference)
//
#include <hip/hip_runtime.h>

// Per-pixel attention over 32 "boxes" (all fp32):
//   q,k,v: [32 box][4 batch][64 ch][6400 pix]
//   scores[i,j] = <q[i,:,p], k[j,:,p]> / 8 ; w = softmax_j ; out[i,c,p] = sum_j w[i,j] v[j,c,p]
//
// R11 vs R10/R9: R10's j-split caused 9x bank conflicts (reverted). R9's profile shows
// NOTHING saturated (VALU 35%, HBM 26%, LDS 10%, Occ 19%): the cost is convoy effects --
// 34 full-block barriers with only 2 blocks/CU to cover them, plus ~22% dispatch-tail
// quantization (1600 blocks / 512 slots).
//
// This round: SINGLE-WAVE BLOCKS, ZERO BARRIERS. NT=64, PIX=4 (lanes = 4 pp x 16 ig,
// s[2][32]=64 regs, R9's proven shape). LDS is private per wave -> no __syncthreads
// anywhere; the compiler's automatic lgkmcnt waits order ds_write->ds_read within the
// wave (race-impossible, R7's failure class structurally gone). LDS reads: 4 unique
// addrs x 16-way broadcast = conflict-free (starts {0,4,8,12}); staging writes 2-way
// (free). 6400 independent 1-wave blocks stream at 4 waves/SIMD with no rendezvous.
// Keeps: 2-deep K/V register prefetch, Q register double-buffer, XCD swizzle (6400%8==0),
// launch_bounds(64,2) -> VGPR cap 128 (empirical law cap=256/arg2; R4/R6-verified).
// Known risk: staging loads are 16B/lane scattered (4-pixel granule); L2 serves the
// 64B-line sharing across neighbor tiles; TA cost ~128 cyc/chunk << 512 compute cyc.

#define NBOX    32
#define NBATCH  4
#define CH      64
#define HW      6400
#define PIX     4
#define CC      4
#define NCHUNK  (CH / CC)          // 16
#define NT      64
#define LPJ     36                 // LDS row stride in floats (32 j + 4 pad)
#define NTILES  (HW / PIX)         // 1600
#define NUNITS  (NBATCH * NTILES)  // 6400
#define CSTRIDE ((size_t)CC * HW)  // elements per chunk step

__global__ __launch_bounds__(NT, 2)
void box_attn_kernel(const float* __restrict__ q,
                     const float* __restrict__ k,
                     const float* __restrict__ v,
                     float* __restrict__ out) {
    __shared__ float lds[2][CC * PIX * LPJ];   // 2 x 2.3 KiB, private to this wave

    const int t   = threadIdx.x;
    const int bid = blockIdx.x;
    const int unit = (bid & 7) * (NUNITS / 8) + (bid >> 3);  // XCD swizzle
    const int b    = unit / NTILES;
    const int p0   = (unit % NTILES) * PIX;

    // compute mapping: lane = pp(2b) | ig(4b)
    const int pp = t & 3;
    const int i0 = (t >> 2) * 2;

    // staging mapping: lane covers (j = t&31, c = t>>5) and c+2 (2nd float4)
    const int jj = t & 31;
    const int cs = t >> 5;               // 0..1
    const size_t g0 = ((size_t)(jj * NBATCH + b) * CH + cs) * HW + p0;  // float4 = 4 pixels
    const size_t gd = (size_t)2 * HW;    // +2 channels for 2nd float4
    const int    l0 = (cs * PIX) * LPJ + jj;   // component p -> +p*LPJ
    const int    ld = 2 * PIX * LPJ;

    const size_t qoff0 = ((size_t)((i0 + 0) * NBATCH + b) * CH) * HW + p0 + pp;
    const size_t qoff1 = ((size_t)((i0 + 1) * NBATCH + b) * CH) * HW + p0 + pp;

    float s0[NBOX], s1[NBOX];
#pragma unroll
    for (int j = 0; j < NBOX; ++j) { s0[j] = 0.f; s1[j] = 0.f; }

    float4 rA0, rA1, rB0, rB1;
    float qf0[CC], qf1[CC], qn0[CC], qn1[CC];

    // ================= Phase 1: scores = Q.K (1/8 folded into softmax) =================
    {   // K chunk 0 -> LDS buf0 (no barrier: in-wave lgkmcnt orders write->read)
        float4 r0 = *reinterpret_cast<const float4*>(k + g0);
        float4 r1 = *reinterpret_cast<const float4*>(k + g0 + gd);
        float* d0 = &lds[0][l0];
        d0[0] = r0.x; d0[LPJ] = r0.y; d0[2 * LPJ] = r0.z; d0[3 * LPJ] = r0.w;
        float* d1 = &lds[0][l0 + ld];
        d1[0] = r1.x; d1[LPJ] = r1.y; d1[2 * LPJ] = r1.z; d1[3 * LPJ] = r1.w;
    }
    rA0 = *reinterpret_cast<const float4*>(k + g0 + CSTRIDE);       // K chunk 1
    rA1 = *reinterpret_cast<const float4*>(k + g0 + CSTRIDE + gd);
#pragma unroll
    for (int c = 0; c < CC; ++c) {                                  // Q chunk 0
        qf0[c] = q[qoff0 + (size_t)c * HW];
        qf1[c] = q[qoff1 + (size_t)c * HW];
    }

#pragma unroll 1
    for (int ch = 0; ch < NCHUNK; ++ch) {
        if (ch + 2 < NCHUNK) {                                      // K chunk ch+2
            const float* src = k + g0 + (size_t)(ch + 2) * CSTRIDE;
            rB0 = *reinterpret_cast<const float4*>(src);
            rB1 = *reinterpret_cast<const float4*>(src + gd);
        }
        if (ch + 1 < NCHUNK) {
#pragma unroll
            for (int c = 0; c < CC; ++c) {                          // Q chunk ch+1
                qn0[c] = q[qoff0 + (size_t)((ch + 1) * CC + c) * HW];
                qn1[c] = q[qoff1 + (size_t)((ch + 1) * CC + c) * HW];
            }
        }

        const float* buf = &lds[ch & 1][0];
#pragma unroll
        for (int c = 0; c < CC; ++c) {
            const float* row = &buf[(c * PIX + pp) * LPJ];
#pragma unroll
            for (int jg = 0; jg < 8; ++jg) {
                float4 kv = *reinterpret_cast<const float4*>(row + jg * 4);
                s0[jg * 4 + 0] = fmaf(qf0[c], kv.x, s0[jg * 4 + 0]);
                s0[jg * 4 + 1] = fmaf(qf0[c], kv.y, s0[jg * 4 + 1]);
                s0[jg * 4 + 2] = fmaf(qf0[c], kv.z, s0[jg * 4 + 2]);
                s0[jg * 4 + 3] = fmaf(qf0[c], kv.w, s0[jg * 4 + 3]);
                s1[jg * 4 + 0] = fmaf(qf1[c], kv.x, s1[jg * 4 + 0]);
                s1[jg * 4 + 1] = fmaf(qf1[c], kv.y, s1[jg * 4 + 1]);
                s1[jg * 4 + 2] = fmaf(qf1[c], kv.z, s1[jg * 4 + 2]);
                s1[jg * 4 + 3] = fmaf(qf1[c], kv.w, s1[jg * 4 + 3]);
            }
        }

        if (ch + 1 < NCHUNK) {    // write K chunk ch+1; next iter's reads wait on lgkmcnt
            float* d0 = &lds[(ch + 1) & 1][l0];
            d0[0] = rA0.x; d0[LPJ] = rA0.y; d0[2 * LPJ] = rA0.z; d0[3 * LPJ] = rA0.w;
            float* d1 = &lds[(ch + 1) & 1][l0 + ld];
            d1[0] = rA1.x; d1[LPJ] = rA1.y; d1[2 * LPJ] = rA1.z; d1[3 * LPJ] = rA1.w;
            rA0 = rB0; rA1 = rB1;
#pragma unroll
            for (int c = 0; c < CC; ++c) { qf0[c] = qn0[c]; qf1[c] = qn1[c]; }
        }
    }

    // ================= softmax over j (fully in-register) =================
    {   // V chunk 0 issued first, lands during softmax
        float4 r0 = *reinterpret_cast<const float4*>(v + g0);
        float4 r1 = *reinterpret_cast<const float4*>(v + g0 + gd);
        float* d0 = &lds[0][l0];
        d0[0] = r0.x; d0[LPJ] = r0.y; d0[2 * LPJ] = r0.z; d0[3 * LPJ] = r0.w;
        float* d1 = &lds[0][l0 + ld];
        d1[0] = r1.x; d1[LPJ] = r1.y; d1[2 * LPJ] = r1.z; d1[3 * LPJ] = r1.w;
    }
    rA0 = *reinterpret_cast<const float4*>(v + g0 + CSTRIDE);       // V chunk 1
    rA1 = *reinterpret_cast<const float4*>(v + g0 + CSTRIDE + gd);
    {
        float m = s0[0];
#pragma unroll
        for (int j = 1; j < NBOX; ++j) m = fmaxf(m, s0[j]);
        float sum = 0.f;
#pragma unroll
        for (int j = 0; j < NBOX; ++j) { float e = __expf((s0[j] - m) * 0.125f); s0[j] = e; sum += e; }
        float inv = 1.f / sum;
#pragma unroll
        for (int j = 0; j < NBOX; ++j) s0[j] *= inv;
    }
    {
        float m = s1[0];
#pragma unroll
        for (int j = 1; j < NBOX; ++j) m = fmaxf(m, s1[j]);
        float sum = 0.f;
#pragma unroll
        for (int j = 0; j < NBOX; ++j) { float e = __expf((s1[j] - m) * 0.125f); s1[j] = e; sum += e; }
        float inv = 1.f / sum;
#pragma unroll
        for (int j = 0; j < NBOX; ++j) s1[j] *= inv;
    }

    // ================= Phase 2: out = W V (V prefetch 2-deep) =================
#pragma unroll 1
    for (int ch = 0; ch < NCHUNK; ++ch) {
        if (ch + 2 < NCHUNK) {                                      // V chunk ch+2
            const float* src = v + g0 + (size_t)(ch + 2) * CSTRIDE;
            rB0 = *reinterpret_cast<const float4*>(src);
            rB1 = *reinterpret_cast<const float4*>(src + gd);
        }

        float acc0[CC], acc1[CC];
#pragma unroll
        for (int c = 0; c < CC; ++c) { acc0[c] = 0.f; acc1[c] = 0.f; }

        const float* buf = &lds[ch & 1][0];
#pragma unroll
        for (int c = 0; c < CC; ++c) {
            const float* row = &buf[(c * PIX + pp) * LPJ];
#pragma unroll
            for (int jg = 0; jg < 8; ++jg) {
                float4 vv = *reinterpret_cast<const float4*>(row + jg * 4);
                acc0[c] = fmaf(s0[jg * 4 + 0], vv.x, acc0[c]);
                acc0[c] = fmaf(s0[jg * 4 + 1], vv.y, acc0[c]);
                acc0[c] = fmaf(s0[jg * 4 + 2], vv.z, acc0[c]);
                acc0[c] = fmaf(s0[jg * 4 + 3], vv.w, acc0[c]);
                acc1[c] = fmaf(s1[jg * 4 + 0], vv.x, acc1[c]);
                acc1[c] = fmaf(s1[jg * 4 + 1], vv.y, acc1[c]);
                acc1[c] = fmaf(s1[jg * 4 + 2], vv.z, acc1[c]);
                acc1[c] = fmaf(s1[jg * 4 + 3], vv.w, acc1[c]);
            }
        }
#pragma unroll
        for (int c = 0; c < CC; ++c) {
            out[qoff0 + (size_t)(ch * CC + c) * HW] = acc0[c];
            out[qoff1 + (size_t)(ch * CC + c) * HW] = acc1[c];
        }

        if (ch + 1 < NCHUNK) {    // write V chunk ch+1
            float* d0 = &lds[(ch + 1) & 1][l0];
            d0[0] = rA0.x; d0[LPJ] = rA0.y; d0[2 * LPJ] = rA0.z; d0[3 * LPJ] = rA0.w;
            float* d1 = &lds[(ch + 1) & 1][l0 + ld];
            d1[0] = rA1.x; d1[LPJ] = rA1.y; d1[2 * LPJ] = rA1.z; d1[3 * LPJ] = rA1.w;
            rA0 = rB0; rA1 = rB1;
        }
    }
}

extern "C" void kernel_launch(void* const* d_in, const int* in_sizes, int n_in,
                              void* d_out, int out_size, void* d_ws, size_t ws_size,
                              hipStream_t stream) {
    const float* q = (const float*)d_in[0];
    const float* k = (const float*)d_in[1];
    const float* v = (const float*)d_in[2];
    float* o = (float*)d_out;
    dim3 grid(NUNITS);   // 6400 single-wave blocks
    box_attn_kernel<<<grid, NT, 0, stream>>>(q, k, v, o);
}

// Round 13
// 232.041 us; speedup vs baseline: 1.6158x; 1.6158x over previous
//
#include <hip/hip_runtime.h>

// Per-pixel attention over 32 "boxes" (fp32 in/out), MFMA f16 compute.
//   q,k,v: [32 box][4 batch][64 ch][6400 pix]
//   S[i,j] = <q[i,:,p],k[j,:,p]>/8 ; w = softmax_j ; out[i,c,p] = sum_j w[i,j] v[j,c,p]
//
// R13 = R12 with the type fix: clang's AMDGPU builtins use __fp16 ('h') — cvt_pkrtz
// returns __fp16x2 and mfma_*_f16 takes __fp16x8. _Float16 is a distinct type (no
// implicit vector conversion) -> typedef __fp16. No other changes.
//
// Design (R12 rationale): R8-R11 showed nothing saturated; the real limiter was the
// VALU design's 16x LDS-read amplification (6.7 GB LDS reads). MFMA does operand reuse
// in the matrix unit: LDS traffic ~16x lower, VALU ~4x lower -> HBM-bound (~130us floor).
// Per pixel (one wave): S^T = K.Q^T via mfma_f32_32x32x16_f16 (M=j,N=i,K=c, 4 mfma,
// c-halves staged 2+2). Softmax over j = D-frag rows, in-register, one shfl_xor(32).
// P -> f16 B-frags with zero cross-lane ops (D-row map (r&3)+8*(r>>2)+4h aligns with
// the operand k-map). O^T = V^T.P^T (2 c-tiles x 2 mfma). sigma-robust: A and B staged/
// packed with the SAME k-map; only the C/D layout matters (HW-verified m74/m101).
// Block = (b, 16px), 8 waves (wave w <-> px {w,w+8}); LDS 64KB phase1 Kf+Qf overlay ->
// phase2 Vf+Obuf; 2 blocks/CU; swz/swzO XOR swizzles (both injective); frag reads
// conflict-free; output staged via Obuf for 64B store sectors; fenced barriers (R7).

#define NBOX    32
#define NBATCH  4
#define CH      64
#define HW      6400
#define PIX     16
#define NT      512
#define NTILES  (HW / PIX)         // 400
#define NUNITS  (NBATCH * NTILES)  // 1600

typedef __fp16 f16;
typedef f16   f16x2  __attribute__((ext_vector_type(2)));
typedef f16   f16x8  __attribute__((ext_vector_type(8)));
typedef float f32x16 __attribute__((ext_vector_type(16)));

#define SYNC() do { __builtin_amdgcn_sched_barrier(0); __syncthreads(); \
                    __builtin_amdgcn_sched_barrier(0); } while (0)

__device__ __forceinline__ int swz(int L) {
    return L ^ ((((L >> 9) & 3) | (((L >> 13) & 1) << 2)) << 4);
}
__device__ __forceinline__ int swzO(int L) {
    return L ^ ((((L >> 10) & 7) ^ ((L >> 5) & 7)) << 4);
}

#define ZERO16 {0.f,0.f,0.f,0.f,0.f,0.f,0.f,0.f,0.f,0.f,0.f,0.f,0.f,0.f,0.f,0.f}

__global__ __launch_bounds__(NT, 2)
void box_attn_mfma(const float* __restrict__ q, const float* __restrict__ k,
                   const float* __restrict__ v, float* __restrict__ out) {
    __shared__ char sm[65536];
    char* const KF = sm;            // phase1: K frags (c-half), 32KB
    char* const QF = sm + 32768;    // phase1: Q frags (c-half), 32KB
    char* const VF = sm;            // phase2: V frags (ct-slice), 32KB
    char* const OB = sm + 32768;    // phase2: O staging f16, 32KB

    const int t    = threadIdx.x;
    const int lane = t & 63;
    const int w    = t >> 6;        // wave 0..7 -> pixels {w, w+8}
    const int h    = lane >> 5;
    const int bid  = blockIdx.x;
    const int unit = (bid & 7) * (NUNITS / 8) + (bid >> 3);   // XCD swizzle
    const int b    = unit / NTILES;
    const int p0   = (unit % NTILES) * PIX;

    auto stage_kq = [&](const float* __restrict__ src, char* reg_, int chalf) {
#pragma unroll
        for (int rep = 0; rep < 2; ++rep) {
            int u = rep * NT + t;
            int pxq = u & 3, qq = (u >> 2) & 3, kcL = (u >> 4) & 1, box = (u >> 5) & 31;
            int cb = chalf + kcL * 16 + qq * 4;
            const float* g = src + ((size_t)((box * NBATCH + b) * CH + cb)) * HW + p0 + pxq * 4;
            float4 l0 = *(const float4*)(g);
            float4 l1 = *(const float4*)(g + HW);
            float4 l2 = *(const float4*)(g + 2 * HW);
            float4 l3 = *(const float4*)(g + 3 * HW);
            const float* f0 = &l0.x; const float* f1 = &l1.x;
            const float* f2 = &l2.x; const float* f3 = &l3.x;
            int Lb = kcL * 1024 + (box + 32 * (qq & 1)) * 16 + (qq >> 1) * 8;
#pragma unroll
            for (int pi = 0; pi < 4; ++pi) {
                union { f16x2 hh[2]; uint2 u2; } val;
                val.hh[0] = __builtin_amdgcn_cvt_pkrtz(f0[pi], f1[pi]);
                val.hh[1] = __builtin_amdgcn_cvt_pkrtz(f2[pi], f3[pi]);
                *(uint2*)(reg_ + swz((pxq * 4 + pi) * 2048 + Lb)) = val.u2;
            }
        }
    };

    auto stage_v = [&](int coff) {   // coff = ct*32
        const size_t JS = (size_t)NBATCH * CH * HW;
#pragma unroll
        for (int rep = 0; rep < 2; ++rep) {
            int u = rep * NT + t;
            int pxq = u & 3, qq = (u >> 2) & 3, jc = (u >> 4) & 1, cL = (u >> 5) & 31;
            const float* g = v + ((size_t)(((jc * 16 + qq * 4) * NBATCH + b) * CH + coff + cL)) * HW
                               + p0 + pxq * 4;
            float4 l0 = *(const float4*)(g);
            float4 l1 = *(const float4*)(g + JS);
            float4 l2 = *(const float4*)(g + 2 * JS);
            float4 l3 = *(const float4*)(g + 3 * JS);
            const float* f0 = &l0.x; const float* f1 = &l1.x;
            const float* f2 = &l2.x; const float* f3 = &l3.x;
            int Lb = jc * 1024 + (cL + 32 * (qq & 1)) * 16 + (qq >> 1) * 8;
#pragma unroll
            for (int pi = 0; pi < 4; ++pi) {
                union { f16x2 hh[2]; uint2 u2; } val;
                val.hh[0] = __builtin_amdgcn_cvt_pkrtz(f0[pi], f1[pi]);
                val.hh[1] = __builtin_amdgcn_cvt_pkrtz(f2[pi], f3[pi]);
                *(uint2*)(VF + swz((pxq * 4 + pi) * 2048 + Lb)) = val.u2;
            }
        }
    };

    auto smax_pack = [&](const f32x16& s, f16x8& fr0, f16x8& fr1) {
        float p[16];
        float m = s[0];
#pragma unroll
        for (int r = 1; r < 16; ++r) m = fmaxf(m, s[r]);
        m = fmaxf(m, __shfl_xor(m, 32, 64));
        float sum = 0.f;
#pragma unroll
        for (int r = 0; r < 16; ++r) { p[r] = __expf((s[r] - m) * 0.125f); sum += p[r]; }
        sum += __shfl_xor(sum, 32, 64);
        float inv = 1.f / sum;
        union { f16x8 v8; f16x2 hh[4]; } u0, u1;
#pragma unroll
        for (int kk = 0; kk < 4; ++kk) {
            u0.hh[kk] = __builtin_amdgcn_cvt_pkrtz(p[2 * kk] * inv,     p[2 * kk + 1] * inv);
            u1.hh[kk] = __builtin_amdgcn_cvt_pkrtz(p[8 + 2 * kk] * inv, p[9 + 2 * kk] * inv);
        }
        fr0 = u0.v8; fr1 = u1.v8;
    };

    // ================= Phase 1: S^T = K . Q^T =================
    f32x16 sA = ZERO16, sB = ZERO16;

    stage_kq(k, KF, 0);
    stage_kq(q, QF, 0);
    SYNC();
#pragma unroll
    for (int kcL = 0; kcL < 2; ++kcL) {
        int LA = kcL * 1024 + lane * 16;
        f16x8 a0 = *(const f16x8*)(KF + swz(w * 2048 + LA));
        f16x8 b0 = *(const f16x8*)(QF + swz(w * 2048 + LA));
        sA = __builtin_amdgcn_mfma_f32_32x32x16_f16(a0, b0, sA, 0, 0, 0);
        f16x8 a1 = *(const f16x8*)(KF + swz((w + 8) * 2048 + LA));
        f16x8 b1 = *(const f16x8*)(QF + swz((w + 8) * 2048 + LA));
        sB = __builtin_amdgcn_mfma_f32_32x32x16_f16(a1, b1, sB, 0, 0, 0);
    }
    SYNC();
    stage_kq(k, KF, 32);
    stage_kq(q, QF, 32);
    SYNC();
#pragma unroll
    for (int kcL = 0; kcL < 2; ++kcL) {
        int LA = kcL * 1024 + lane * 16;
        f16x8 a0 = *(const f16x8*)(KF + swz(w * 2048 + LA));
        f16x8 b0 = *(const f16x8*)(QF + swz(w * 2048 + LA));
        sA = __builtin_amdgcn_mfma_f32_32x32x16_f16(a0, b0, sA, 0, 0, 0);
        f16x8 a1 = *(const f16x8*)(KF + swz((w + 8) * 2048 + LA));
        f16x8 b1 = *(const f16x8*)(QF + swz((w + 8) * 2048 + LA));
        sB = __builtin_amdgcn_mfma_f32_32x32x16_f16(a1, b1, sB, 0, 0, 0);
    }
    SYNC();   // all Kf/Qf reads done -> VF region reusable

    stage_v(0);                       // overlaps softmax (no LDS in softmax)
    f16x8 pA0, pA1, pB0, pB1;
    smax_pack(sA, pA0, pA1);
    smax_pack(sB, pB0, pB1);
    SYNC();                           // V ct0 staged

    // ================= Phase 2: O^T = V^T . P^T per c-tile =================
#pragma unroll
    for (int ct = 0; ct < 2; ++ct) {
        f32x16 oA = ZERO16, oB = ZERO16;
        {
            int LA = lane * 16;
            f16x8 av0 = *(const f16x8*)(VF + swz(w * 2048 + LA));
            oA = __builtin_amdgcn_mfma_f32_32x32x16_f16(av0, pA0, oA, 0, 0, 0);
            f16x8 av1 = *(const f16x8*)(VF + swz((w + 8) * 2048 + LA));
            oB = __builtin_amdgcn_mfma_f32_32x32x16_f16(av1, pB0, oB, 0, 0, 0);
        }
        {
            int LA = 1024 + lane * 16;
            f16x8 av0 = *(const f16x8*)(VF + swz(w * 2048 + LA));
            oA = __builtin_amdgcn_mfma_f32_32x32x16_f16(av0, pA1, oA, 0, 0, 0);
            f16x8 av1 = *(const f16x8*)(VF + swz((w + 8) * 2048 + LA));
            oB = __builtin_amdgcn_mfma_f32_32x32x16_f16(av1, pB1, oB, 0, 0, 0);
        }
        const int i = lane & 31;
#pragma unroll
        for (int r = 0; r < 16; ++r) {
            int cL = (r & 3) + 8 * (r >> 2) + 4 * h;
            *(f16*)(OB + swzO(i * 1024 + cL * 32 + w * 2))       = (f16)oA[r];
            *(f16*)(OB + swzO(i * 1024 + cL * 32 + (w + 8) * 2)) = (f16)oB[r];
        }
        SYNC();   // Obuf complete; VF readers done

        if (ct == 0) stage_v(32);     // stage V ct1 while out-writing ct0

#pragma unroll
        for (int rep = 0; rep < 2; ++rep) {
            int row = rep * NT + t;   // 1024 rows = 32 i x 32 cL
            int oi = row >> 5, cL = row & 31;
            union { uint4 u4; f16x2 hh[4]; } ra, rb;
            ra.u4 = *(const uint4*)(OB + swzO(oi * 1024 + cL * 32));
            rb.u4 = *(const uint4*)(OB + swzO(oi * 1024 + cL * 32 + 16));
            float* op = out + ((size_t)((oi * NBATCH + b) * CH + ct * 32 + cL)) * HW + p0;
            float4 s0 = { (float)ra.hh[0][0], (float)ra.hh[0][1], (float)ra.hh[1][0], (float)ra.hh[1][1] };
            float4 s1 = { (float)ra.hh[2][0], (float)ra.hh[2][1], (float)ra.hh[3][0], (float)ra.hh[3][1] };
            float4 s2 = { (float)rb.hh[0][0], (float)rb.hh[0][1], (float)rb.hh[1][0], (float)rb.hh[1][1] };
            float4 s3 = { (float)rb.hh[2][0], (float)rb.hh[2][1], (float)rb.hh[3][0], (float)rb.hh[3][1] };
            *(float4*)(op + 0)  = s0;
            *(float4*)(op + 4)  = s1;
            *(float4*)(op + 8)  = s2;
            *(float4*)(op + 12) = s3;
        }
        if (ct == 0) SYNC();   // V ct1 staged; Obuf readers done before ct1 frag-writes
    }
}

extern "C" void kernel_launch(void* const* d_in, const int* in_sizes, int n_in,
                              void* d_out, int out_size, void* d_ws, size_t ws_size,
                              hipStream_t stream) {
    const float* q = (const float*)d_in[0];
    const float* k = (const float*)d_in[1];
    const float* v = (const float*)d_in[2];
    float* o = (float*)d_out;
    dim3 grid(NUNITS);   // 1600 blocks of 512
    box_attn_mfma<<<grid, NT, 0, stream>>>(q, k, v, o);
}

// Round 14
// 221.570 us; speedup vs baseline: 1.6922x; 1.0473x over previous
//
#include <hip/hip_runtime.h>

// Per-pixel attention over 32 "boxes" (fp32 in/out), MFMA f16 compute.
//   q,k,v: [32 box][4 batch][64 ch][6400 pix]
//   S[i,j] = <q[i,:,p],k[j,:,p]>/8 ; w = softmax_j ; out[i,c,p] = sum_j w[i,j] v[j,c,p]
//
// R14 vs R13: R13 passed (absmax 0.0156) and proved the MFMA thesis (VALU 35->6.9%,
// VGPR 64) but stayed at 232us: each of ~6 global-load stages paid its full ~900cy HBM
// latency inline (loads issued after the preceding barrier), 2 blocks/CU. This round is
// pure T14 (issue-early / write-late): every stage's global loads are issued >=1 compute
// phase + 2 barriers before their pack+LDS-write:
//   K1/Q1 issued during MFMA half0; V0 issued during MFMA half1; V1 issued before
//   softmax (lands under softmax + PV ct0).
// Geometry/swizzles/barriers identical to R13. Peak reg audit ~115 < 128 cap.
// Spill signature to watch: VGPR=128 AND WRITE >> 208MB -> stagger prefetch next.

#define NBOX    32
#define NBATCH  4
#define CH      64
#define HW      6400
#define PIX     16
#define NT      512
#define NTILES  (HW / PIX)         // 400
#define NUNITS  (NBATCH * NTILES)  // 1600

typedef __fp16 f16;
typedef f16   f16x2  __attribute__((ext_vector_type(2)));
typedef f16   f16x8  __attribute__((ext_vector_type(8)));
typedef float f32x16 __attribute__((ext_vector_type(16)));

#define SYNC() do { __builtin_amdgcn_sched_barrier(0); __syncthreads(); \
                    __builtin_amdgcn_sched_barrier(0); } while (0)

__device__ __forceinline__ int swz(int L) {
    return L ^ ((((L >> 9) & 3) | (((L >> 13) & 1) << 2)) << 4);
}
__device__ __forceinline__ int swzO(int L) {
    return L ^ ((((L >> 10) & 7) ^ ((L >> 5) & 7)) << 4);
}

#define ZERO16 {0.f,0.f,0.f,0.f,0.f,0.f,0.f,0.f,0.f,0.f,0.f,0.f,0.f,0.f,0.f,0.f}

__global__ __launch_bounds__(NT, 2)
void box_attn_mfma(const float* __restrict__ q, const float* __restrict__ k,
                   const float* __restrict__ v, float* __restrict__ out) {
    __shared__ char sm[65536];
    char* const KF = sm;            // phase1: K frags (c-half), 32KB
    char* const QF = sm + 32768;    // phase1: Q frags (c-half), 32KB
    char* const VF = sm;            // phase2: V frags (ct-slice), 32KB
    char* const OB = sm + 32768;    // phase2: O staging f16, 32KB

    const int t    = threadIdx.x;
    const int lane = t & 63;
    const int w    = t >> 6;        // wave 0..7 -> pixels {w, w+8}
    const int h    = lane >> 5;
    const int bid  = blockIdx.x;
    const int unit = (bid & 7) * (NUNITS / 8) + (bid >> 3);   // XCD swizzle
    const int b    = unit / NTILES;
    const int p0   = (unit % NTILES) * PIX;

    // ---- T14 split staging: load (global->regs) and write (pack->LDS) ----
    auto load_kq = [&](const float* __restrict__ src, int chalf, float4* r) {
#pragma unroll
        for (int rep = 0; rep < 2; ++rep) {
            int u = rep * NT + t;
            int pxq = u & 3, qq = (u >> 2) & 3, kcL = (u >> 4) & 1, box = (u >> 5) & 31;
            int cb = chalf + kcL * 16 + qq * 4;
            const float* g = src + ((size_t)((box * NBATCH + b) * CH + cb)) * HW + p0 + pxq * 4;
            r[rep * 4 + 0] = *(const float4*)(g);
            r[rep * 4 + 1] = *(const float4*)(g + HW);
            r[rep * 4 + 2] = *(const float4*)(g + 2 * HW);
            r[rep * 4 + 3] = *(const float4*)(g + 3 * HW);
        }
    };
    auto write_kq = [&](char* dst, const float4* r) {
#pragma unroll
        for (int rep = 0; rep < 2; ++rep) {
            int u = rep * NT + t;
            int pxq = u & 3, qq = (u >> 2) & 3, kcL = (u >> 4) & 1, box = (u >> 5) & 31;
            int Lb = kcL * 1024 + (box + 32 * (qq & 1)) * 16 + (qq >> 1) * 8;
            const float* f0 = &r[rep * 4 + 0].x;
            const float* f1 = &r[rep * 4 + 1].x;
            const float* f2 = &r[rep * 4 + 2].x;
            const float* f3 = &r[rep * 4 + 3].x;
#pragma unroll
            for (int pi = 0; pi < 4; ++pi) {
                union { f16x2 hh[2]; uint2 u2; } val;
                val.hh[0] = __builtin_amdgcn_cvt_pkrtz(f0[pi], f1[pi]);
                val.hh[1] = __builtin_amdgcn_cvt_pkrtz(f2[pi], f3[pi]);
                *(uint2*)(dst + swz((pxq * 4 + pi) * 2048 + Lb)) = val.u2;
            }
        }
    };
    auto load_v = [&](int coff, float4* r) {   // coff = ct*32
        const size_t JS = (size_t)NBATCH * CH * HW;
#pragma unroll
        for (int rep = 0; rep < 2; ++rep) {
            int u = rep * NT + t;
            int pxq = u & 3, qq = (u >> 2) & 3, jc = (u >> 4) & 1, cL = (u >> 5) & 31;
            const float* g = v + ((size_t)(((jc * 16 + qq * 4) * NBATCH + b) * CH + coff + cL)) * HW
                               + p0 + pxq * 4;
            r[rep * 4 + 0] = *(const float4*)(g);
            r[rep * 4 + 1] = *(const float4*)(g + JS);
            r[rep * 4 + 2] = *(const float4*)(g + 2 * JS);
            r[rep * 4 + 3] = *(const float4*)(g + 3 * JS);
        }
    };
    auto write_v = [&](const float4* r) {
#pragma unroll
        for (int rep = 0; rep < 2; ++rep) {
            int u = rep * NT + t;
            int pxq = u & 3, qq = (u >> 2) & 3, jc = (u >> 4) & 1, cL = (u >> 5) & 31;
            int Lb = jc * 1024 + (cL + 32 * (qq & 1)) * 16 + (qq >> 1) * 8;
            const float* f0 = &r[rep * 4 + 0].x;
            const float* f1 = &r[rep * 4 + 1].x;
            const float* f2 = &r[rep * 4 + 2].x;
            const float* f3 = &r[rep * 4 + 3].x;
#pragma unroll
            for (int pi = 0; pi < 4; ++pi) {
                union { f16x2 hh[2]; uint2 u2; } val;
                val.hh[0] = __builtin_amdgcn_cvt_pkrtz(f0[pi], f1[pi]);
                val.hh[1] = __builtin_amdgcn_cvt_pkrtz(f2[pi], f3[pi]);
                *(uint2*)(VF + swz((pxq * 4 + pi) * 2048 + Lb)) = val.u2;
            }
        }
    };

    auto smax_pack = [&](const f32x16& s, f16x8& fr0, f16x8& fr1) {
        float p[16];
        float m = s[0];
#pragma unroll
        for (int r = 1; r < 16; ++r) m = fmaxf(m, s[r]);
        m = fmaxf(m, __shfl_xor(m, 32, 64));
        float sum = 0.f;
#pragma unroll
        for (int r = 0; r < 16; ++r) { p[r] = __expf((s[r] - m) * 0.125f); sum += p[r]; }
        sum += __shfl_xor(sum, 32, 64);
        float inv = 1.f / sum;
        union { f16x8 v8; f16x2 hh[4]; } u0, u1;
#pragma unroll
        for (int kk = 0; kk < 4; ++kk) {
            u0.hh[kk] = __builtin_amdgcn_cvt_pkrtz(p[2 * kk] * inv,     p[2 * kk + 1] * inv);
            u1.hh[kk] = __builtin_amdgcn_cvt_pkrtz(p[8 + 2 * kk] * inv, p[9 + 2 * kk] * inv);
        }
        fr0 = u0.v8; fr1 = u1.v8;
    };

    // ================= Phase 1: S^T = K . Q^T =================
    f32x16 sA = ZERO16, sB = ZERO16;
    float4 kr[8], qr[8], vr[8];

    load_kq(k, 0, kr);  load_kq(q, 0, qr);
    write_kq(KF, kr);   write_kq(QF, qr);    // first stage: latency unavoidable
    load_kq(k, 32, kr); load_kq(q, 32, qr);  // T14: K1/Q1 in flight across MFMA half0
    SYNC();
#pragma unroll
    for (int kcL = 0; kcL < 2; ++kcL) {
        int LA = kcL * 1024 + lane * 16;
        f16x8 a0 = *(const f16x8*)(KF + swz(w * 2048 + LA));
        f16x8 b0 = *(const f16x8*)(QF + swz(w * 2048 + LA));
        sA = __builtin_amdgcn_mfma_f32_32x32x16_f16(a0, b0, sA, 0, 0, 0);
        f16x8 a1 = *(const f16x8*)(KF + swz((w + 8) * 2048 + LA));
        f16x8 b1 = *(const f16x8*)(QF + swz((w + 8) * 2048 + LA));
        sB = __builtin_amdgcn_mfma_f32_32x32x16_f16(a1, b1, sB, 0, 0, 0);
    }
    SYNC();
    write_kq(KF, kr); write_kq(QF, qr);      // pack+write only (loads landed)
    load_v(0, vr);                           // T14: V0 in flight across MFMA half1
    SYNC();
#pragma unroll
    for (int kcL = 0; kcL < 2; ++kcL) {
        int LA = kcL * 1024 + lane * 16;
        f16x8 a0 = *(const f16x8*)(KF + swz(w * 2048 + LA));
        f16x8 b0 = *(const f16x8*)(QF + swz(w * 2048 + LA));
        sA = __builtin_amdgcn_mfma_f32_32x32x16_f16(a0, b0, sA, 0, 0, 0);
        f16x8 a1 = *(const f16x8*)(KF + swz((w + 8) * 2048 + LA));
        f16x8 b1 = *(const f16x8*)(QF + swz((w + 8) * 2048 + LA));
        sB = __builtin_amdgcn_mfma_f32_32x32x16_f16(a1, b1, sB, 0, 0, 0);
    }
    SYNC();   // all Kf/Qf reads done -> VF region reusable

    write_v(vr);                             // V0 -> VF (loads landed)
    load_v(32, vr);                          // T14: V1 in flight across softmax + PV ct0
    f16x8 pA0, pA1, pB0, pB1;
    smax_pack(sA, pA0, pA1);
    smax_pack(sB, pB0, pB1);
    SYNC();                                  // V0 staged

    // ================= Phase 2: O^T = V^T . P^T =================
    // ---- ct = 0 ----
    {
        f32x16 oA = ZERO16, oB = ZERO16;
        {
            int LA = lane * 16;
            f16x8 av0 = *(const f16x8*)(VF + swz(w * 2048 + LA));
            oA = __builtin_amdgcn_mfma_f32_32x32x16_f16(av0, pA0, oA, 0, 0, 0);
            f16x8 av1 = *(const f16x8*)(VF + swz((w + 8) * 2048 + LA));
            oB = __builtin_amdgcn_mfma_f32_32x32x16_f16(av1, pB0, oB, 0, 0, 0);
        }
        {
            int LA = 1024 + lane * 16;
            f16x8 av0 = *(const f16x8*)(VF + swz(w * 2048 + LA));
            oA = __builtin_amdgcn_mfma_f32_32x32x16_f16(av0, pA1, oA, 0, 0, 0);
            f16x8 av1 = *(const f16x8*)(VF + swz((w + 8) * 2048 + LA));
            oB = __builtin_amdgcn_mfma_f32_32x32x16_f16(av1, pB1, oB, 0, 0, 0);
        }
        const int i = lane & 31;
#pragma unroll
        for (int r = 0; r < 16; ++r) {
            int cL = (r & 3) + 8 * (r >> 2) + 4 * h;
            *(f16*)(OB + swzO(i * 1024 + cL * 32 + w * 2))       = (f16)oA[r];
            *(f16*)(OB + swzO(i * 1024 + cL * 32 + (w + 8) * 2)) = (f16)oB[r];
        }
        SYNC();   // OB complete; VF readers done

        write_v(vr);   // V1 -> VF (loaded long ago; landed under softmax+PV)

#pragma unroll
        for (int rep = 0; rep < 2; ++rep) {
            int row = rep * NT + t;
            int oi = row >> 5, cL = row & 31;
            union { uint4 u4; f16x2 hh[4]; } ra, rb;
            ra.u4 = *(const uint4*)(OB + swzO(oi * 1024 + cL * 32));
            rb.u4 = *(const uint4*)(OB + swzO(oi * 1024 + cL * 32 + 16));
            float* op = out + ((size_t)((oi * NBATCH + b) * CH + cL)) * HW + p0;
            float4 s0 = { (float)ra.hh[0][0], (float)ra.hh[0][1], (float)ra.hh[1][0], (float)ra.hh[1][1] };
            float4 s1 = { (float)ra.hh[2][0], (float)ra.hh[2][1], (float)ra.hh[3][0], (float)ra.hh[3][1] };
            float4 s2 = { (float)rb.hh[0][0], (float)rb.hh[0][1], (float)rb.hh[1][0], (float)rb.hh[1][1] };
            float4 s3 = { (float)rb.hh[2][0], (float)rb.hh[2][1], (float)rb.hh[3][0], (float)rb.hh[3][1] };
            *(float4*)(op + 0)  = s0;
            *(float4*)(op + 4)  = s1;
            *(float4*)(op + 8)  = s2;
            *(float4*)(op + 12) = s3;
        }
        SYNC();   // V1 staged; OB readers done before ct1 frag-writes
    }
    // ---- ct = 1 ----
    {
        f32x16 oA = ZERO16, oB = ZERO16;
        {
            int LA = lane * 16;
            f16x8 av0 = *(const f16x8*)(VF + swz(w * 2048 + LA));
            oA = __builtin_amdgcn_mfma_f32_32x32x16_f16(av0, pA0, oA, 0, 0, 0);
            f16x8 av1 = *(const f16x8*)(VF + swz((w + 8) * 2048 + LA));
            oB = __builtin_amdgcn_mfma_f32_32x32x16_f16(av1, pB0, oB, 0, 0, 0);
        }
        {
            int LA = 1024 + lane * 16;
            f16x8 av0 = *(const f16x8*)(VF + swz(w * 2048 + LA));
            oA = __builtin_amdgcn_mfma_f32_32x32x16_f16(av0, pA1, oA, 0, 0, 0);
            f16x8 av1 = *(const f16x8*)(VF + swz((w + 8) * 2048 + LA));
            oB = __builtin_amdgcn_mfma_f32_32x32x16_f16(av1, pB1, oB, 0, 0, 0);
        }
        const int i = lane & 31;
#pragma unroll
        for (int r = 0; r < 16; ++r) {
            int cL = (r & 3) + 8 * (r >> 2) + 4 * h;
            *(f16*)(OB + swzO(i * 1024 + cL * 32 + w * 2))       = (f16)oA[r];
            *(f16*)(OB + swzO(i * 1024 + cL * 32 + (w + 8) * 2)) = (f16)oB[r];
        }
        SYNC();   // OB complete

#pragma unroll
        for (int rep = 0; rep < 2; ++rep) {
            int row = rep * NT + t;
            int oi = row >> 5, cL = row & 31;
            union { uint4 u4; f16x2 hh[4]; } ra, rb;
            ra.u4 = *(const uint4*)(OB + swzO(oi * 1024 + cL * 32));
            rb.u4 = *(const uint4*)(OB + swzO(oi * 1024 + cL * 32 + 16));
            float* op = out + ((size_t)((oi * NBATCH + b) * CH + 32 + cL)) * HW + p0;
            float4 s0 = { (float)ra.hh[0][0], (float)ra.hh[0][1], (float)ra.hh[1][0], (float)ra.hh[1][1] };
            float4 s1 = { (float)ra.hh[2][0], (float)ra.hh[2][1], (float)ra.hh[3][0], (float)ra.hh[3][1] };
            float4 s2 = { (float)rb.hh[0][0], (float)rb.hh[0][1], (float)rb.hh[1][0], (float)rb.hh[1][1] };
            float4 s3 = { (float)rb.hh[2][0], (float)rb.hh[2][1], (float)rb.hh[3][0], (float)rb.hh[3][1] };
            *(float4*)(op + 0)  = s0;
            *(float4*)(op + 4)  = s1;
            *(float4*)(op + 8)  = s2;
            *(float4*)(op + 12) = s3;
        }
    }
}

extern "C" void kernel_launch(void* const* d_in, const int* in_sizes, int n_in,
                              void* d_out, int out_size, void* d_ws, size_t ws_size,
                              hipStream_t stream) {
    const float* q = (const float*)d_in[0];
    const float* k = (const float*)d_in[1];
    const float* v = (const float*)d_in[2];
    float* o = (float*)d_out;
    dim3 grid(NUNITS);   // 1600 blocks of 512
    box_attn_mfma<<<grid, NT, 0, stream>>>(q, k, v, o);
}